// Round 4
// baseline (524.977 us; speedup 1.0000x reference)
//
#include <hip/hip_runtime.h>
#include <math.h>

// Problem constants
#define BB   32
#define SS   512
#define EE   256
#define HH   8
#define LL   4
#define FFD  1024
#define DHD  32

constexpr float LN_EPS = 1e-5f;
constexpr int   NBSE   = BB * SS * EE;   // 4,194,304

typedef float  f32x4  __attribute__((ext_vector_type(4)));
typedef __bf16 bf16;
typedef __bf16 bf16x4 __attribute__((ext_vector_type(4)));
typedef __bf16 bf16x8 __attribute__((ext_vector_type(8)));

// tanh-form GELU (|err| vs exact erf-GELU ~1e-3, safe within bf16 tolerance)
__device__ __forceinline__ float gelu_f(float x) {
    float u = x * x;
    float t = 1.5957691216057308f * x * (1.0f + 0.044715f * u);
    return x / (1.0f + __expf(-t));
}

// ---------------------------------------------------------------- merged weight prep
__global__ __launch_bounds__(256) void k_prep(const float* __restrict__ W1,
                                              const float* __restrict__ W2,
                                              const float* __restrict__ Wq,
                                              const float* __restrict__ Wk,
                                              const float* __restrict__ Wv,
                                              bf16* __restrict__ W1t,
                                              bf16* __restrict__ W2t,
                                              bf16* __restrict__ Wqt,
                                              bf16* __restrict__ Wkt,
                                              bf16* __restrict__ Wvt) {
    __shared__ float tile[32][33];
    int bid = blockIdx.x;
    int tx = threadIdx.x & 31, ty = threadIdx.x >> 5;   // 32 x 8
    if (bid < 2048) {
        bool isw2 = bid >= 1024;
        int id = isw2 ? bid - 1024 : bid;
        int K = isw2 ? FFD : EE, N = isw2 ? EE : FFD;
        int l = id >> 8, rem = id & 255;
        int n0, k0;
        if (isw2) { n0 = (rem & 7) * 32;  k0 = (rem >> 3) * 32; }
        else      { n0 = (rem & 31) * 32; k0 = (rem >> 5) * 32; }
        const float* in = (isw2 ? W2 : W1) + (size_t)l * K * N;
        bf16* out       = (isw2 ? W2t : W1t) + (size_t)l * K * N;
        #pragma unroll
        for (int i = 0; i < 32; i += 8)
            tile[ty + i][tx] = in[(size_t)(k0 + ty + i) * N + n0 + tx];
        __syncthreads();
        #pragma unroll
        for (int i = 0; i < 32; i += 8)
            out[(size_t)(n0 + ty + i) * K + k0 + tx] = (bf16)tile[tx][ty + i];
    } else {
        int id = bid - 2048;
        int lh = id & 31, z = id >> 5;
        const float* in = (z == 0 ? Wq : z == 1 ? Wk : Wv) + (size_t)lh * 1024;
        bf16* out       = (z == 0 ? Wqt : z == 1 ? Wkt : Wvt) + (size_t)lh * 1024;
        float scale = (z == 0) ? 0.17677669529663687f : 1.0f;
        #pragma unroll
        for (int i = 0; i < 32; i += 8)
            tile[ty + i][tx] = in[(ty + i) * 32 + tx];
        __syncthreads();
        #pragma unroll
        for (int i = 0; i < 32; i += 8)
            out[(ty + i) * 32 + tx] = (bf16)(tile[tx][ty + i] * scale);
    }
}

// ---------------------------------------------------------------- fused (addpos+)LN+QKV (MFMA)
// grid (B, S/32); 4 waves. LN: wave w owns 8 s-rows. MFMA: wave = (rowtile rt=w&1,
// headgroup w>>1 -> 4 heads). 512 blocks -> 2 blocks/CU.
template <bool ADDPOS>
__global__ __launch_bounds__(256) void k_lnqkv(const float* __restrict__ xin,
                                               const float* __restrict__ pos,
                                               float* __restrict__ hout,
                                               const bf16* __restrict__ Wqt,
                                               const bf16* __restrict__ Wkt,
                                               const bf16* __restrict__ Wvt,
                                               bf16* __restrict__ qb,
                                               bf16* __restrict__ kb,
                                               bf16* __restrict__ vb) {
    __shared__ __attribute__((aligned(16))) bf16 Xs[32 * 264];
    int b = blockIdx.x, s0 = blockIdx.y * 32;
    int tid = threadIdx.x, w = tid >> 6, lane = tid & 63;
    size_t rowoff = ((size_t)(b * SS + s0 + w * 8)) * EE + lane * 4;
    const float* hb = xin + rowoff;
    float4 pv;
    if (ADDPOS) pv = *(const float4*)(pos + lane * 4);
    float4 xr[8];
    #pragma unroll
    for (int i = 0; i < 8; i++)
        xr[i] = *(const float4*)(hb + (size_t)i * EE);
    if (ADDPOS) {
        #pragma unroll
        for (int i = 0; i < 8; i++) {
            xr[i].x += pv.x; xr[i].y += pv.y; xr[i].z += pv.z; xr[i].w += pv.w;
            *(float4*)(hout + rowoff + (size_t)i * EE) = xr[i];
        }
    }
    #pragma unroll
    for (int i = 0; i < 8; i++) {
        float4 v4 = xr[i];
        float sum = v4.x + v4.y + v4.z + v4.w;
        #pragma unroll
        for (int m = 1; m <= 32; m <<= 1) sum += __shfl_xor(sum, m, 64);
        float mean = sum * (1.0f / EE);
        float dx = v4.x - mean, dy = v4.y - mean, dz = v4.z - mean, dw = v4.w - mean;
        float ss = dx * dx + dy * dy + dz * dz + dw * dw;
        #pragma unroll
        for (int m = 1; m <= 32; m <<= 1) ss += __shfl_xor(ss, m, 64);
        float rstd = rsqrtf(ss * (1.0f / EE) + LN_EPS);
        bf16x4 o4 = { (bf16)(dx * rstd), (bf16)(dy * rstd), (bf16)(dz * rstd), (bf16)(dw * rstd) };
        *(bf16x4*)&Xs[(w * 8 + i) * 264 + lane * 4] = o4;
    }
    __syncthreads();
    int col = lane & 15, quad = lane >> 4;
    int rt = w & 1, hgrp = w >> 1;
    #pragma unroll
    for (int hh2 = 0; hh2 < 4; hh2++) {
        int h = hgrp * 4 + hh2;
        bf16x8 a = *(const bf16x8*)&Xs[(rt * 16 + col) * 264 + h * 32 + quad * 8];
        size_t base = ((size_t)((b * HH + h) * SS) + s0 + rt * 16) * DHD;
        #pragma unroll
        for (int nt = 0; nt < 2; nt++) {
            int e = nt * 16 + col;
            bf16x8 bq  = *(const bf16x8*)(Wqt + (h * 32 + e) * 32 + quad * 8);
            bf16x8 bk2 = *(const bf16x8*)(Wkt + (h * 32 + e) * 32 + quad * 8);
            bf16x8 bv2 = *(const bf16x8*)(Wvt + (h * 32 + e) * 32 + quad * 8);
            f32x4 z = {0.f, 0.f, 0.f, 0.f};
            f32x4 cq = __builtin_amdgcn_mfma_f32_16x16x32_bf16(bq, a, z, 0, 0, 0);
            f32x4 ck = __builtin_amdgcn_mfma_f32_16x16x32_bf16(bk2, a, z, 0, 0, 0);
            f32x4 cv = __builtin_amdgcn_mfma_f32_16x16x32_bf16(a, bv2, z, 0, 0, 0);
            bf16x4 q4 = { (bf16)cq[0], (bf16)cq[1], (bf16)cq[2], (bf16)cq[3] };
            bf16x4 k4 = { (bf16)ck[0], (bf16)ck[1], (bf16)ck[2], (bf16)ck[3] };
            size_t tb = base + (size_t)col * DHD + nt * 16 + quad * 4;
            *(bf16x4*)&qb[tb] = q4;
            *(bf16x4*)&kb[tb] = k4;
            bf16x4 vv = { (bf16)cv[0], (bf16)cv[1], (bf16)cv[2], (bf16)cv[3] };
            *(bf16x4*)&vb[(((size_t)(b * HH + h)) * DHD + e) * SS + s0 + rt * 16 + quad * 4] = vv;
        }
    }
}

// ---------------------------------------------------------------- MFMA flash attention v3
#define ATT_LDK 40
#define ATT_LDV 264
#define ATT_LDP 36
__global__ __launch_bounds__(256) void k_attn(const bf16* __restrict__ Q,
                                              const bf16* __restrict__ K,
                                              const bf16* __restrict__ VT,
                                              bf16* __restrict__ O) {
    __shared__ __attribute__((aligned(16))) bf16 Ks[256 * ATT_LDK];
    __shared__ __attribute__((aligned(16))) bf16 Vs[32 * ATT_LDV];
    __shared__ __attribute__((aligned(16))) bf16 Ps[4][16 * ATT_LDP];
    int bh = blockIdx.x;
    int q0 = blockIdx.y * 128;
    int tid = threadIdx.x;
    int w = tid >> 6, lane = tid & 63;
    int col = lane & 15, quad = lane >> 4;
    bf16x8 aq[2];
    #pragma unroll
    for (int sub = 0; sub < 2; sub++)
        aq[sub] = *(const bf16x8*)(Q + ((size_t)(bh * SS + q0 + sub * 64 + w * 16 + col)) * DHD + quad * 8);
    float lr[2] = {0.f, 0.f};
    f32x4 oacc[2][2] = {};
    int ksr = tid >> 2, ksc = (tid & 3) * 8;   // K staging: 64 rows/iter x 32 d
    int vd  = tid >> 5, vso = (tid & 31) * 8;  // VT staging: 8 d-rows/pass x 256 s
    bf16x8 kr[4], vr[4];
    #pragma unroll
    for (int it = 0; it < 4; it++) {
        kr[it] = *(const bf16x8*)(K + ((size_t)(bh * SS + it * 64 + ksr)) * DHD + ksc);
        vr[it] = *(const bf16x8*)(VT + (((size_t)bh * DHD + it * 8 + vd) * SS) + vso);
    }
    for (int ph = 0; ph < 2; ph++) {
        __syncthreads();
        #pragma unroll
        for (int it = 0; it < 4; it++) {
            *(bf16x8*)&Ks[(it * 64 + ksr) * ATT_LDK + ksc] = kr[it];
            *(bf16x8*)&Vs[(it * 8 + vd) * ATT_LDV + vso] = vr[it];
        }
        if (ph == 0) {
            #pragma unroll
            for (int it = 0; it < 4; it++) {
                kr[it] = *(const bf16x8*)(K + ((size_t)(bh * SS + 256 + it * 64 + ksr)) * DHD + ksc);
                vr[it] = *(const bf16x8*)(VT + (((size_t)bh * DHD + it * 8 + vd) * SS) + 256 + vso);
            }
        }
        __syncthreads();
        #pragma unroll
        for (int i = 0; i < 8; i++) {
            bf16x8 bk[2], bv[2];
            #pragma unroll
            for (int nt = 0; nt < 2; nt++) {
                bk[nt] = *(const bf16x8*)&Ks[(i * 32 + nt * 16 + col) * ATT_LDK + quad * 8];
                bv[nt] = *(const bf16x8*)&Vs[(nt * 16 + col) * ATT_LDV + i * 32 + quad * 8];
            }
            __builtin_amdgcn_s_setprio(1);
            #pragma unroll
            for (int sub = 0; sub < 2; sub++) {
                #pragma unroll
                for (int nt = 0; nt < 2; nt++) {
                    f32x4 z = {0.f, 0.f, 0.f, 0.f};
                    f32x4 st = __builtin_amdgcn_mfma_f32_16x16x32_bf16(bk[nt], aq[sub], z, 0, 0, 0);
                    bf16x4 p4;
                    #pragma unroll
                    for (int r = 0; r < 4; r++) {
                        float p = __expf(st[r]);
                        lr[sub] += p;
                        p4[r] = (bf16)p;
                    }
                    *(bf16x4*)&Ps[w][col * ATT_LDP + nt * 16 + quad * 4] = p4;
                }
                bf16x4 apl = *(const bf16x4*)&Ps[w][col * ATT_LDP + quad * 8];
                bf16x4 aph = *(const bf16x4*)&Ps[w][col * ATT_LDP + quad * 8 + 4];
                bf16x8 ap;
                ap[0] = apl[0]; ap[1] = apl[1]; ap[2] = apl[2]; ap[3] = apl[3];
                ap[4] = aph[0]; ap[5] = aph[1]; ap[6] = aph[2]; ap[7] = aph[3];
                #pragma unroll
                for (int nt = 0; nt < 2; nt++)
                    oacc[sub][nt] = __builtin_amdgcn_mfma_f32_16x16x32_bf16(ap, bv[nt], oacc[sub][nt], 0, 0, 0);
            }
            __builtin_amdgcn_s_setprio(0);
        }
    }
    int b = bh >> 3, hh = bh & 7;
    #pragma unroll
    for (int sub = 0; sub < 2; sub++) {
        float ls = lr[sub];
        ls += __shfl_xor(ls, 16, 64);
        ls += __shfl_xor(ls, 32, 64);
        #pragma unroll
        for (int r = 0; r < 4; r++) {
            float lrow = __shfl(ls, quad * 4 + r, 64);
            float inv = 1.0f / lrow;
            int row = q0 + sub * 64 + w * 16 + quad * 4 + r;
            size_t ob = ((size_t)(b * SS + row)) * EE + hh * 32;
            O[ob + col]      = (bf16)(oacc[sub][0][r] * inv);
            O[ob + 16 + col] = (bf16)(oacc[sub][1][r] * inv);
        }
    }
}

// ---------------------------------------------------------------- fully fused FFN v2
// Weights are L2-resident and per-lane fragments are contiguous 16B -> load them
// DIRECTLY global->VGPR (no LDS staging, no ring, no vmcnt choreography).
// LDS keeps only cross-wave-reuse data: As 32KB + Gs 16KB + b1s 4KB = 52KB
// -> 2 blocks/CU (16 waves). Barriers: 2 per ff-chunk (Gs handoff only),
// raw s_barrier + lgkmcnt(0) (no vmcnt drain -> weight loads flow across).
// MFMA summation order identical to v1 (ks=p*2+kk, fs=j*2+kk) -> same absmax.
__global__ __launch_bounds__(512, 4) void k_ffn(const bf16* __restrict__ ob,
                                                const float* __restrict__ hb,
                                                const bf16* __restrict__ W1t_l,
                                                const float* __restrict__ b1_l,
                                                const bf16* __restrict__ W2t_l,
                                                const float* __restrict__ b2_l,
                                                float* __restrict__ Cf) {
    __shared__ __attribute__((aligned(16))) bf16 As[64 * 256];      // 32 KB resident
    __shared__ __attribute__((aligned(16))) bf16 Gs[64 * 128];      // 16 KB
    __shared__ __attribute__((aligned(16))) float b1s[FFD];         // 4 KB
    int tid = threadIdx.x, w = tid >> 6, lane = tid & 63;
    int col = lane & 15, quad = lane >> 4;
    int rg = w >> 2, cg = w & 3;          // row-group (2x32 rows), col-group
    int row0 = blockIdx.x * 64;

    // b1 -> LDS
    *(float2*)&b1s[tid * 2] = *(const float2*)&b1_l[tid * 2];

    // ---- fused residual + LN prologue: wave w rows w*8 .. w*8+7
    #pragma unroll 2
    for (int rr = 0; rr < 8; rr++) {
        int r = w * 8 + rr;
        size_t g = (size_t)(row0 + r) * EE + lane * 4;
        float4 h4 = *(const float4*)(hb + g);
        bf16x4 o4 = *(const bf16x4*)(ob + g);
        float v0 = h4.x + (float)o4[0], v1 = h4.y + (float)o4[1];
        float v2 = h4.z + (float)o4[2], v3 = h4.w + (float)o4[3];
        float s1 = v0 + v1 + v2 + v3;
        float s2 = v0 * v0 + v1 * v1 + v2 * v2 + v3 * v3;
        #pragma unroll
        for (int m = 1; m <= 32; m <<= 1) {
            s1 += __shfl_xor(s1, m, 64);
            s2 += __shfl_xor(s2, m, 64);
        }
        float mean = s1 * (1.0f / EE);
        float rstd = rsqrtf(s2 * (1.0f / EE) - mean * mean + LN_EPS);
        bf16x4 a4 = { (bf16)((v0 - mean) * rstd), (bf16)((v1 - mean) * rstd),
                      (bf16)((v2 - mean) * rstd), (bf16)((v3 - mean) * rstd) };
        *(bf16x4*)&As[r * 256 + ((lane * 4) ^ ((r & 7) << 3))] = a4;
    }
    __syncthreads();    // As, b1s visible

    f32x4 accO[2][4] = {};
    const bf16* W1p = W1t_l + (size_t)(cg * 32 + col) * EE + quad * 8;
    const bf16* W2p = W2t_l + (size_t)(cg * 64 + col) * FFD + quad * 8;

    for (int ch = 0; ch < 8; ch++) {
        // ---- W1 phase: accG = As @ W1chunk (K=256, 8 k-steps of 32), no barriers
        f32x4 accG[2][2] = {};
        #pragma unroll
        for (int ks = 0; ks < 8; ks++) {
            bf16x8 bfr[2], af[2];
            #pragma unroll
            for (int nt = 0; nt < 2; nt++)
                bfr[nt] = *(const bf16x8*)(W1p + (size_t)(ch * 128 + nt * 16) * EE + ks * 32);
            #pragma unroll
            for (int mt = 0; mt < 2; mt++) {
                int r = rg * 32 + mt * 16 + col;
                af[mt] = *(const bf16x8*)&As[r * 256 + ((ks * 32 + quad * 8) ^ ((r & 7) << 3))];
            }
            #pragma unroll
            for (int mt = 0; mt < 2; mt++)
                #pragma unroll
                for (int nt = 0; nt < 2; nt++)
                    accG[mt][nt] = __builtin_amdgcn_mfma_f32_16x16x32_bf16(bfr[nt], af[mt], accG[mt][nt], 0, 0, 0);
        }
        // ---- G = gelu(accG + b1) -> Gs (swizzled)
        #pragma unroll
        for (int mt = 0; mt < 2; mt++) {
            int t = rg * 32 + mt * 16 + col;
            #pragma unroll
            for (int nt = 0; nt < 2; nt++) {
                int f = cg * 32 + nt * 16 + quad * 4;
                float4 b4 = *(const float4*)&b1s[ch * 128 + f];
                bf16x4 g4;
                g4[0] = (bf16)gelu_f(accG[mt][nt][0] + b4.x);
                g4[1] = (bf16)gelu_f(accG[mt][nt][1] + b4.y);
                g4[2] = (bf16)gelu_f(accG[mt][nt][2] + b4.z);
                g4[3] = (bf16)gelu_f(accG[mt][nt][3] + b4.w);
                *(bf16x4*)&Gs[t * 128 + (f ^ ((t & 7) << 3))] = g4;
            }
        }
        // prefetch fs=0 W2 frags (independent of Gs -> issued before barrier)
        bf16x8 bf2p[4];
        #pragma unroll
        for (int nt = 0; nt < 4; nt++)
            bf2p[nt] = *(const bf16x8*)(W2p + (size_t)(nt * 16) * FFD + ch * 128);
        asm volatile("s_waitcnt lgkmcnt(0)" ::: "memory");   // Gs writes visible
        __builtin_amdgcn_s_barrier();
        // ---- W2 phase: accO += G @ W2chunk (ffk=128, 4 steps of 32)
        #pragma unroll
        for (int fs = 0; fs < 4; fs++) {
            bf16x8 bf2[4], af2[2];
            #pragma unroll
            for (int nt = 0; nt < 4; nt++)
                bf2[nt] = (fs == 0) ? bf2p[nt]
                        : *(const bf16x8*)(W2p + (size_t)(nt * 16) * FFD + ch * 128 + fs * 32);
            #pragma unroll
            for (int mt = 0; mt < 2; mt++) {
                int r = rg * 32 + mt * 16 + col;
                af2[mt] = *(const bf16x8*)&Gs[r * 128 + ((fs * 32 + quad * 8) ^ ((r & 7) << 3))];
            }
            #pragma unroll
            for (int mt = 0; mt < 2; mt++)
                #pragma unroll
                for (int nt = 0; nt < 4; nt++)
                    accO[mt][nt] = __builtin_amdgcn_mfma_f32_16x16x32_bf16(bf2[nt], af2[mt], accO[mt][nt], 0, 0, 0);
        }
        // Gs reads complete (lgkm waits precede the MFMAs) -> safe to overwrite next chunk
        __builtin_amdgcn_s_barrier();
    }
    // ---- epilogue: + b2 + residual (h + ob), f32 out
    #pragma unroll
    for (int mt = 0; mt < 2; mt++) {
        int row = row0 + rg * 32 + mt * 16 + col;
        #pragma unroll
        for (int nt = 0; nt < 4; nt++) {
            int cc = cg * 64 + nt * 16 + quad * 4;
            float4 b4 = *(const float4*)&b2_l[cc];
            float4 h4 = *(const float4*)&hb[(size_t)row * EE + cc];
            bf16x4 o4 = *(const bf16x4*)&ob[(size_t)row * EE + cc];
            float4 out;
            out.x = accO[mt][nt][0] + b4.x + h4.x + (float)o4[0];
            out.y = accO[mt][nt][1] + b4.y + h4.y + (float)o4[1];
            out.z = accO[mt][nt][2] + b4.z + h4.z + (float)o4[2];
            out.w = accO[mt][nt][3] + b4.w + h4.w + (float)o4[3];
            *(float4*)&Cf[(size_t)row * EE + cc] = out;
        }
    }
}

// ---------------------------------------------------------------- launch
extern "C" void kernel_launch(void* const* d_in, const int* in_sizes, int n_in,
                              void* d_out, int out_size, void* d_ws, size_t ws_size,
                              hipStream_t stream) {
    (void)in_sizes; (void)n_in; (void)out_size; (void)ws_size;
    const float* x   = (const float*)d_in[0];
    const float* pos = (const float*)d_in[1];
    const float* Wq  = (const float*)d_in[2];
    const float* Wk  = (const float*)d_in[3];
    const float* Wv  = (const float*)d_in[4];
    const float* W1  = (const float*)d_in[5];
    const float* b1  = (const float*)d_in[6];
    const float* W2  = (const float*)d_in[7];
    const float* b2  = (const float*)d_in[8];

    float* ws = (float*)d_ws;
    size_t N = (size_t)NBSE;
    float* h  = ws;                          // [0 .. 16MB) f32 residual stream
    bf16* ob  = (bf16*)(ws + N);             // [16 .. 24MB) attention out, concat layout
    bf16* qb  = (bf16*)(ws + 2 * N);         // [32 .. 40MB)
    bf16* kb  = qb + N;                      // [40 .. 48MB)
    bf16* vb  = kb + N;                      // [48 .. 56MB) (VT layout [bh][d][s])
    bf16* W1t = (bf16*)(ws + 4 * N);         // [64MB ..)
    bf16* W2t = W1t + (size_t)LL * EE * FFD;
    bf16* Wqt = W2t + (size_t)LL * EE * FFD;
    bf16* Wkt = Wqt + (size_t)LL * HH * DHD * DHD;
    bf16* Wvt = Wkt + (size_t)LL * HH * DHD * DHD;

    k_prep<<<2144, 256, 0, stream>>>(W1, W2, Wq, Wk, Wv, W1t, W2t, Wqt, Wkt, Wvt);
    for (int l = 0; l < LL; l++) {
        if (l == 0)
            k_lnqkv<true><<<dim3(BB, SS / 32), 256, 0, stream>>>(
                x, pos, h, Wqt, Wkt, Wvt, qb, kb, vb);
        else
            k_lnqkv<false><<<dim3(BB, SS / 32), 256, 0, stream>>>(
                h, nullptr, nullptr,
                Wqt + (size_t)l * HH * DHD * DHD, Wkt + (size_t)l * HH * DHD * DHD,
                Wvt + (size_t)l * HH * DHD * DHD, qb, kb, vb);
        k_attn<<<dim3(BB * HH, SS / 128), 256, 0, stream>>>(qb, kb, vb, ob);
        float* outp = (l == LL - 1) ? (float*)d_out : h;
        k_ffn<<<BB * SS / 64, 512, 0, stream>>>(
            ob, h, W1t + (size_t)l * FFD * EE, b1 + (size_t)l * FFD,
            W2t + (size_t)l * EE * FFD, b2 + (size_t)l * EE, outp);
    }
}

// Round 5
// 389.990 us; speedup vs baseline: 1.3461x; 1.3461x over previous
//
#include <hip/hip_runtime.h>
#include <math.h>

// Problem constants
#define BB   32
#define SS   512
#define EE   256
#define HH   8
#define LL   4
#define FFD  1024
#define DHD  32

constexpr float LN_EPS = 1e-5f;
constexpr int   NBSE   = BB * SS * EE;   // 4,194,304

typedef float  f32x4  __attribute__((ext_vector_type(4)));
typedef __bf16 bf16;
typedef __bf16 bf16x4 __attribute__((ext_vector_type(4)));
typedef __bf16 bf16x8 __attribute__((ext_vector_type(8)));

#define WAITV(n) asm volatile("s_waitcnt vmcnt(" #n ")" ::: "memory")

// async global->LDS, 16B per lane; LDS dest is wave-uniform base + lane*16B
__device__ __forceinline__ void glds16(const bf16* g, bf16* l) {
    __builtin_amdgcn_global_load_lds(
        (const __attribute__((address_space(1))) void*)g,
        (__attribute__((address_space(3))) void*)l,
        16, 0, 0);
}

// tanh-form GELU (|err| vs exact erf-GELU ~1e-3, safe within bf16 tolerance)
__device__ __forceinline__ float gelu_f(float x) {
    float u = x * x;
    float t = 1.5957691216057308f * x * (1.0f + 0.044715f * u);
    return x / (1.0f + __expf(-t));
}

// ---------------------------------------------------------------- merged weight prep
__global__ __launch_bounds__(256) void k_prep(const float* __restrict__ W1,
                                              const float* __restrict__ W2,
                                              const float* __restrict__ Wq,
                                              const float* __restrict__ Wk,
                                              const float* __restrict__ Wv,
                                              bf16* __restrict__ W1t,
                                              bf16* __restrict__ W2t,
                                              bf16* __restrict__ Wqt,
                                              bf16* __restrict__ Wkt,
                                              bf16* __restrict__ Wvt) {
    __shared__ float tile[32][33];
    int bid = blockIdx.x;
    int tx = threadIdx.x & 31, ty = threadIdx.x >> 5;   // 32 x 8
    if (bid < 2048) {
        bool isw2 = bid >= 1024;
        int id = isw2 ? bid - 1024 : bid;
        int K = isw2 ? FFD : EE, N = isw2 ? EE : FFD;
        int l = id >> 8, rem = id & 255;
        int n0, k0;
        if (isw2) { n0 = (rem & 7) * 32;  k0 = (rem >> 3) * 32; }
        else      { n0 = (rem & 31) * 32; k0 = (rem >> 5) * 32; }
        const float* in = (isw2 ? W2 : W1) + (size_t)l * K * N;
        bf16* out       = (isw2 ? W2t : W1t) + (size_t)l * K * N;
        #pragma unroll
        for (int i = 0; i < 32; i += 8)
            tile[ty + i][tx] = in[(size_t)(k0 + ty + i) * N + n0 + tx];
        __syncthreads();
        #pragma unroll
        for (int i = 0; i < 32; i += 8)
            out[(size_t)(n0 + ty + i) * K + k0 + tx] = (bf16)tile[tx][ty + i];
    } else {
        int id = bid - 2048;
        int lh = id & 31, z = id >> 5;
        const float* in = (z == 0 ? Wq : z == 1 ? Wk : Wv) + (size_t)lh * 1024;
        bf16* out       = (z == 0 ? Wqt : z == 1 ? Wkt : Wvt) + (size_t)lh * 1024;
        float scale = (z == 0) ? 0.17677669529663687f : 1.0f;
        #pragma unroll
        for (int i = 0; i < 32; i += 8)
            tile[ty + i][tx] = in[(ty + i) * 32 + tx];
        __syncthreads();
        #pragma unroll
        for (int i = 0; i < 32; i += 8)
            out[(ty + i) * 32 + tx] = (bf16)(tile[tx][ty + i] * scale);
    }
}

// ---------------------------------------------------------------- fused (addpos+)LN+QKV (MFMA)
template <bool ADDPOS>
__global__ __launch_bounds__(256) void k_lnqkv(const float* __restrict__ xin,
                                               const float* __restrict__ pos,
                                               float* __restrict__ hout,
                                               const bf16* __restrict__ Wqt,
                                               const bf16* __restrict__ Wkt,
                                               const bf16* __restrict__ Wvt,
                                               bf16* __restrict__ qb,
                                               bf16* __restrict__ kb,
                                               bf16* __restrict__ vb) {
    __shared__ __attribute__((aligned(16))) bf16 Xs[32 * 264];
    int b = blockIdx.x, s0 = blockIdx.y * 32;
    int tid = threadIdx.x, w = tid >> 6, lane = tid & 63;
    size_t rowoff = ((size_t)(b * SS + s0 + w * 8)) * EE + lane * 4;
    const float* hb = xin + rowoff;
    float4 pv;
    if (ADDPOS) pv = *(const float4*)(pos + lane * 4);
    float4 xr[8];
    #pragma unroll
    for (int i = 0; i < 8; i++)
        xr[i] = *(const float4*)(hb + (size_t)i * EE);
    if (ADDPOS) {
        #pragma unroll
        for (int i = 0; i < 8; i++) {
            xr[i].x += pv.x; xr[i].y += pv.y; xr[i].z += pv.z; xr[i].w += pv.w;
            *(float4*)(hout + rowoff + (size_t)i * EE) = xr[i];
        }
    }
    #pragma unroll
    for (int i = 0; i < 8; i++) {
        float4 v4 = xr[i];
        float sum = v4.x + v4.y + v4.z + v4.w;
        #pragma unroll
        for (int m = 1; m <= 32; m <<= 1) sum += __shfl_xor(sum, m, 64);
        float mean = sum * (1.0f / EE);
        float dx = v4.x - mean, dy = v4.y - mean, dz = v4.z - mean, dw = v4.w - mean;
        float ss = dx * dx + dy * dy + dz * dz + dw * dw;
        #pragma unroll
        for (int m = 1; m <= 32; m <<= 1) ss += __shfl_xor(ss, m, 64);
        float rstd = rsqrtf(ss * (1.0f / EE) + LN_EPS);
        bf16x4 o4 = { (bf16)(dx * rstd), (bf16)(dy * rstd), (bf16)(dz * rstd), (bf16)(dw * rstd) };
        *(bf16x4*)&Xs[(w * 8 + i) * 264 + lane * 4] = o4;
    }
    __syncthreads();
    int col = lane & 15, quad = lane >> 4;
    int rt = w & 1, hgrp = w >> 1;
    #pragma unroll
    for (int hh2 = 0; hh2 < 4; hh2++) {
        int h = hgrp * 4 + hh2;
        bf16x8 a = *(const bf16x8*)&Xs[(rt * 16 + col) * 264 + h * 32 + quad * 8];
        size_t base = ((size_t)((b * HH + h) * SS) + s0 + rt * 16) * DHD;
        #pragma unroll
        for (int nt = 0; nt < 2; nt++) {
            int e = nt * 16 + col;
            bf16x8 bq  = *(const bf16x8*)(Wqt + (h * 32 + e) * 32 + quad * 8);
            bf16x8 bk2 = *(const bf16x8*)(Wkt + (h * 32 + e) * 32 + quad * 8);
            bf16x8 bv2 = *(const bf16x8*)(Wvt + (h * 32 + e) * 32 + quad * 8);
            f32x4 z = {0.f, 0.f, 0.f, 0.f};
            f32x4 cq = __builtin_amdgcn_mfma_f32_16x16x32_bf16(bq, a, z, 0, 0, 0);
            f32x4 ck = __builtin_amdgcn_mfma_f32_16x16x32_bf16(bk2, a, z, 0, 0, 0);
            f32x4 cv = __builtin_amdgcn_mfma_f32_16x16x32_bf16(a, bv2, z, 0, 0, 0);
            bf16x4 q4 = { (bf16)cq[0], (bf16)cq[1], (bf16)cq[2], (bf16)cq[3] };
            bf16x4 k4 = { (bf16)ck[0], (bf16)ck[1], (bf16)ck[2], (bf16)ck[3] };
            size_t tb = base + (size_t)col * DHD + nt * 16 + quad * 4;
            *(bf16x4*)&qb[tb] = q4;
            *(bf16x4*)&kb[tb] = k4;
            bf16x4 vv = { (bf16)cv[0], (bf16)cv[1], (bf16)cv[2], (bf16)cv[3] };
            *(bf16x4*)&vb[(((size_t)(b * HH + h)) * DHD + e) * SS + s0 + rt * 16 + quad * 4] = vv;
        }
    }
}

// ---------------------------------------------------------------- MFMA flash attention v3
#define ATT_LDK 40
#define ATT_LDV 264
#define ATT_LDP 36
__global__ __launch_bounds__(256) void k_attn(const bf16* __restrict__ Q,
                                              const bf16* __restrict__ K,
                                              const bf16* __restrict__ VT,
                                              bf16* __restrict__ O) {
    __shared__ __attribute__((aligned(16))) bf16 Ks[256 * ATT_LDK];
    __shared__ __attribute__((aligned(16))) bf16 Vs[32 * ATT_LDV];
    __shared__ __attribute__((aligned(16))) bf16 Ps[4][16 * ATT_LDP];
    int bh = blockIdx.x;
    int q0 = blockIdx.y * 128;
    int tid = threadIdx.x;
    int w = tid >> 6, lane = tid & 63;
    int col = lane & 15, quad = lane >> 4;
    bf16x8 aq[2];
    #pragma unroll
    for (int sub = 0; sub < 2; sub++)
        aq[sub] = *(const bf16x8*)(Q + ((size_t)(bh * SS + q0 + sub * 64 + w * 16 + col)) * DHD + quad * 8);
    float lr[2] = {0.f, 0.f};
    f32x4 oacc[2][2] = {};
    int ksr = tid >> 2, ksc = (tid & 3) * 8;   // K staging: 64 rows/iter x 32 d
    int vd  = tid >> 5, vso = (tid & 31) * 8;  // VT staging: 8 d-rows/pass x 256 s
    bf16x8 kr[4], vr[4];
    #pragma unroll
    for (int it = 0; it < 4; it++) {
        kr[it] = *(const bf16x8*)(K + ((size_t)(bh * SS + it * 64 + ksr)) * DHD + ksc);
        vr[it] = *(const bf16x8*)(VT + (((size_t)bh * DHD + it * 8 + vd) * SS) + vso);
    }
    for (int ph = 0; ph < 2; ph++) {
        __syncthreads();
        #pragma unroll
        for (int it = 0; it < 4; it++) {
            *(bf16x8*)&Ks[(it * 64 + ksr) * ATT_LDK + ksc] = kr[it];
            *(bf16x8*)&Vs[(it * 8 + vd) * ATT_LDV + vso] = vr[it];
        }
        if (ph == 0) {
            #pragma unroll
            for (int it = 0; it < 4; it++) {
                kr[it] = *(const bf16x8*)(K + ((size_t)(bh * SS + 256 + it * 64 + ksr)) * DHD + ksc);
                vr[it] = *(const bf16x8*)(VT + (((size_t)bh * DHD + it * 8 + vd) * SS) + 256 + vso);
            }
        }
        __syncthreads();
        #pragma unroll
        for (int i = 0; i < 8; i++) {
            bf16x8 bk[2], bv[2];
            #pragma unroll
            for (int nt = 0; nt < 2; nt++) {
                bk[nt] = *(const bf16x8*)&Ks[(i * 32 + nt * 16 + col) * ATT_LDK + quad * 8];
                bv[nt] = *(const bf16x8*)&Vs[(nt * 16 + col) * ATT_LDV + i * 32 + quad * 8];
            }
            __builtin_amdgcn_s_setprio(1);
            #pragma unroll
            for (int sub = 0; sub < 2; sub++) {
                #pragma unroll
                for (int nt = 0; nt < 2; nt++) {
                    f32x4 z = {0.f, 0.f, 0.f, 0.f};
                    f32x4 st = __builtin_amdgcn_mfma_f32_16x16x32_bf16(bk[nt], aq[sub], z, 0, 0, 0);
                    bf16x4 p4;
                    #pragma unroll
                    for (int r = 0; r < 4; r++) {
                        float p = __expf(st[r]);
                        lr[sub] += p;
                        p4[r] = (bf16)p;
                    }
                    *(bf16x4*)&Ps[w][col * ATT_LDP + nt * 16 + quad * 4] = p4;
                }
                bf16x4 apl = *(const bf16x4*)&Ps[w][col * ATT_LDP + quad * 8];
                bf16x4 aph = *(const bf16x4*)&Ps[w][col * ATT_LDP + quad * 8 + 4];
                bf16x8 ap;
                ap[0] = apl[0]; ap[1] = apl[1]; ap[2] = apl[2]; ap[3] = apl[3];
                ap[4] = aph[0]; ap[5] = aph[1]; ap[6] = aph[2]; ap[7] = aph[3];
                #pragma unroll
                for (int nt = 0; nt < 2; nt++)
                    oacc[sub][nt] = __builtin_amdgcn_mfma_f32_16x16x32_bf16(ap, bv[nt], oacc[sub][nt], 0, 0, 0);
            }
            __builtin_amdgcn_s_setprio(0);
        }
    }
    int b = bh >> 3, hh = bh & 7;
    #pragma unroll
    for (int sub = 0; sub < 2; sub++) {
        float ls = lr[sub];
        ls += __shfl_xor(ls, 16, 64);
        ls += __shfl_xor(ls, 32, 64);
        #pragma unroll
        for (int r = 0; r < 4; r++) {
            float lrow = __shfl(ls, quad * 4 + r, 64);
            float inv = 1.0f / lrow;
            int row = q0 + sub * 64 + w * 16 + quad * 4 + r;
            size_t ob = ((size_t)(b * SS + row)) * EE + hh * 32;
            O[ob + col]      = (bf16)(oacc[sub][0][r] * inv);
            O[ob + 16 + col] = (bf16)(oacc[sub][1][r] * inv);
        }
    }
}

// ---------------------------------------------------------------- fully fused FFN v3
// r3 ring structure (glds16 staging, counted vmcnt) with 32-row/256-thread blocks:
// grid 512 -> 2 INDEPENDENT blocks/CU (fixes r3's 1-block lockstep; r4 post-mortem:
// direct global->VGPR weights = unpipelined latency chain, MfmaUtil 7%).
// LDS: As 16K + Gs 8K + b1s 4K + ring 2x16K = 60KB. Uniform 16KB stage units
// (4 glds16/thread), staged 2 units ahead. 64 units fully unrolled (static idx).
// Unit u: 0-3 = W1 (k = u*64); 4-7 = W2 (j=(u-4)>>1 ffk-half, eh=(u-4)&1 e-half).
// MFMA k-order identical to r3/r4 -> same absmax.
__global__ __launch_bounds__(256, 2) void k_ffn(const bf16* __restrict__ ob,
                                                const float* __restrict__ hb,
                                                const bf16* __restrict__ W1t_l,
                                                const float* __restrict__ b1_l,
                                                const bf16* __restrict__ W2t_l,
                                                const float* __restrict__ b2_l,
                                                float* __restrict__ Cf) {
    __shared__ __attribute__((aligned(16))) bf16 As[32 * 256];     // 16 KB resident
    __shared__ __attribute__((aligned(16))) bf16 Gs[32 * 128];     // 8 KB
    __shared__ __attribute__((aligned(16))) bf16 Bst[2][8192];     // 2 x 16 KB ring
    __shared__ __attribute__((aligned(16))) float b1s[FFD];        // 4 KB
    int tid = threadIdx.x, w = tid >> 6, lane = tid & 63;
    int col = lane & 15, quad = lane >> 4;
    int rg = w >> 1, cg = w & 1;          // row-group (16 rows), col-group
    int row0 = blockIdx.x * 32;

    int srow = tid >> 3;                  // staging row within 32-row call chunk
    int spos = tid & 7;                   // 16B slot within 128B row
    // stage unit g (0..63): ch = g>>3, u = g&7; slot = g&1; 4 glds16/thread.
    auto stage = [&](int g) {
        int ch = g >> 3, u = g & 7, slot = g & 1;
        if (u < 4) {           // W1: 128 ff-rows x 64 k (k = u*64)
            #pragma unroll
            for (int i = 0; i < 4; i++) {
                int r = i * 32 + srow;
                glds16(W1t_l + (size_t)(ch * 128 + r) * EE + u * 64 + ((spos ^ (r & 7)) * 8),
                       &Bst[slot][i * 2048 + w * 512]);
            }
        } else {               // W2: 128 e-rows (eh half) x 64 ffk (j half)
            int j = (u - 4) >> 1, eh = (u - 4) & 1;
            #pragma unroll
            for (int i = 0; i < 4; i++) {
                int r = i * 32 + srow;
                glds16(W2t_l + (size_t)(eh * 128 + r) * FFD + ch * 128 + j * 64 + ((spos ^ (r & 7)) * 8),
                       &Bst[slot][i * 2048 + w * 512]);
            }
        }
    };
    stage(0);
    stage(1);

    // b1 -> LDS
    *(float4*)&b1s[tid * 4] = *(const float4*)&b1_l[tid * 4];

    // ---- fused residual + LN prologue: wave w rows w*8 .. w*8+7
    #pragma unroll 2
    for (int rr = 0; rr < 8; rr++) {
        int r = w * 8 + rr;
        size_t g = (size_t)(row0 + r) * EE + lane * 4;
        float4 h4 = *(const float4*)(hb + g);
        bf16x4 o4 = *(const bf16x4*)(ob + g);
        float v0 = h4.x + (float)o4[0], v1 = h4.y + (float)o4[1];
        float v2 = h4.z + (float)o4[2], v3 = h4.w + (float)o4[3];
        float s1 = v0 + v1 + v2 + v3;
        float s2 = v0 * v0 + v1 * v1 + v2 * v2 + v3 * v3;
        #pragma unroll
        for (int m = 1; m <= 32; m <<= 1) {
            s1 += __shfl_xor(s1, m, 64);
            s2 += __shfl_xor(s2, m, 64);
        }
        float mean = s1 * (1.0f / EE);
        float rstd = rsqrtf(s2 * (1.0f / EE) - mean * mean + LN_EPS);
        bf16x4 a4 = { (bf16)((v0 - mean) * rstd), (bf16)((v1 - mean) * rstd),
                      (bf16)((v2 - mean) * rstd), (bf16)((v3 - mean) * rstd) };
        *(bf16x4*)&As[r * 256 + ((lane * 4) ^ ((r & 7) << 3))] = a4;
    }
    __syncthreads();   // As/b1s visible; drains vmcnt -> units 0,1 resident

    // accO: 16 rows x 128 e per wave (e tile nta: e = nta*32 + cg*16)
    f32x4 accO[8] = {};
    int ar = rg * 16 + col;               // token row for A/G fragments
    int arx = (ar & 7) << 3;

    #pragma unroll
    for (int ch = 0; ch < 8; ch++) {
        f32x4 accG[4] = {};
        #pragma unroll
        for (int u = 0; u < 8; u++) {
            const int g = ch * 8 + u, slot = u & 1;
            if (g < 63) { WAITV(4); } else { WAITV(0); }
            __builtin_amdgcn_s_barrier();
            if (u < 4) {
                // ---- W1 unit: accG += As(k=u*64..+63) @ W1
                bf16x8 af[2];
                #pragma unroll
                for (int kk = 0; kk < 2; kk++)
                    af[kk] = *(const bf16x8*)&As[ar * 256 + ((u * 64 + kk * 32 + quad * 8) ^ arx)];
                #pragma unroll
                for (int nt = 0; nt < 4; nt++) {
                    int c = cg * 64 + nt * 16 + col;
                    #pragma unroll
                    for (int kk = 0; kk < 2; kk++) {
                        bf16x8 bfr = *(const bf16x8*)&Bst[slot][c * 64 + ((kk * 32 + quad * 8) ^ ((c & 7) << 3))];
                        accG[nt] = __builtin_amdgcn_mfma_f32_16x16x32_bf16(bfr, af[kk], accG[nt], 0, 0, 0);
                    }
                }
                if (u == 3) {
                    // ---- G = gelu(accG + b1) -> Gs (swizzled)
                    #pragma unroll
                    for (int nt = 0; nt < 4; nt++) {
                        int f = cg * 64 + nt * 16 + quad * 4;
                        float4 b4 = *(const float4*)&b1s[ch * 128 + f];
                        bf16x4 g4;
                        g4[0] = (bf16)gelu_f(accG[nt][0] + b4.x);
                        g4[1] = (bf16)gelu_f(accG[nt][1] + b4.y);
                        g4[2] = (bf16)gelu_f(accG[nt][2] + b4.z);
                        g4[3] = (bf16)gelu_f(accG[nt][3] + b4.w);
                        *(bf16x4*)&Gs[ar * 128 + (f ^ arx)] = g4;
                    }
                    asm volatile("s_waitcnt lgkmcnt(0)" ::: "memory");  // publish Gs
                }
            } else {
                // ---- W2 unit: accO[eh half] += Gs(ffk=j*64..+63) @ W2
                const int j = (u - 4) >> 1, eh = (u - 4) & 1;
                bf16x8 af2[2];
                #pragma unroll
                for (int kk = 0; kk < 2; kk++)
                    af2[kk] = *(const bf16x8*)&Gs[ar * 128 + ((j * 64 + kk * 32 + quad * 8) ^ arx)];
                #pragma unroll
                for (int nt = 0; nt < 4; nt++) {
                    int c = nt * 32 + cg * 16 + col;   // e row within slot half
                    #pragma unroll
                    for (int kk = 0; kk < 2; kk++) {
                        bf16x8 bfr = *(const bf16x8*)&Bst[slot][c * 64 + ((kk * 32 + quad * 8) ^ ((c & 7) << 3))];
                        accO[eh * 4 + nt] = __builtin_amdgcn_mfma_f32_16x16x32_bf16(bfr, af2[kk], accO[eh * 4 + nt], 0, 0, 0);
                    }
                }
            }
            __builtin_amdgcn_s_barrier();   // slot reads done -> restage safe
            if (g + 2 < 64) stage(g + 2);   // depth-2 prefetch into slot g&1
        }
    }

    // ---- epilogue: + b2 + residual (h + ob), f32 out
    #pragma unroll
    for (int nta = 0; nta < 8; nta++) {
        int eh = nta >> 2;
        int row = row0 + rg * 16 + col;
        int cc = eh * 128 + (nta & 3) * 32 + cg * 16 + quad * 4;
        float4 b4 = *(const float4*)&b2_l[cc];
        float4 h4 = *(const float4*)&hb[(size_t)row * EE + cc];
        bf16x4 o4 = *(const bf16x4*)&ob[(size_t)row * EE + cc];
        float4 out;
        out.x = accO[nta][0] + b4.x + h4.x + (float)o4[0];
        out.y = accO[nta][1] + b4.y + h4.y + (float)o4[1];
        out.z = accO[nta][2] + b4.z + h4.z + (float)o4[2];
        out.w = accO[nta][3] + b4.w + h4.w + (float)o4[3];
        *(float4*)&Cf[(size_t)row * EE + cc] = out;
    }
}

// ---------------------------------------------------------------- launch
extern "C" void kernel_launch(void* const* d_in, const int* in_sizes, int n_in,
                              void* d_out, int out_size, void* d_ws, size_t ws_size,
                              hipStream_t stream) {
    (void)in_sizes; (void)n_in; (void)out_size; (void)ws_size;
    const float* x   = (const float*)d_in[0];
    const float* pos = (const float*)d_in[1];
    const float* Wq  = (const float*)d_in[2];
    const float* Wk  = (const float*)d_in[3];
    const float* Wv  = (const float*)d_in[4];
    const float* W1  = (const float*)d_in[5];
    const float* b1  = (const float*)d_in[6];
    const float* W2  = (const float*)d_in[7];
    const float* b2  = (const float*)d_in[8];

    float* ws = (float*)d_ws;
    size_t N = (size_t)NBSE;
    float* h  = ws;                          // [0 .. 16MB) f32 residual stream
    bf16* ob  = (bf16*)(ws + N);             // [16 .. 24MB) attention out, concat layout
    bf16* qb  = (bf16*)(ws + 2 * N);         // [32 .. 40MB)
    bf16* kb  = qb + N;                      // [40 .. 48MB)
    bf16* vb  = kb + N;                      // [48 .. 56MB) (VT layout [bh][d][s])
    bf16* W1t = (bf16*)(ws + 4 * N);         // [64MB ..)
    bf16* W2t = W1t + (size_t)LL * EE * FFD;
    bf16* Wqt = W2t + (size_t)LL * EE * FFD;
    bf16* Wkt = Wqt + (size_t)LL * HH * DHD * DHD;
    bf16* Wvt = Wkt + (size_t)LL * HH * DHD * DHD;

    k_prep<<<2144, 256, 0, stream>>>(W1, W2, Wq, Wk, Wv, W1t, W2t, Wqt, Wkt, Wvt);
    for (int l = 0; l < LL; l++) {
        if (l == 0)
            k_lnqkv<true><<<dim3(BB, SS / 32), 256, 0, stream>>>(
                x, pos, h, Wqt, Wkt, Wvt, qb, kb, vb);
        else
            k_lnqkv<false><<<dim3(BB, SS / 32), 256, 0, stream>>>(
                h, nullptr, nullptr,
                Wqt + (size_t)l * HH * DHD * DHD, Wkt + (size_t)l * HH * DHD * DHD,
                Wvt + (size_t)l * HH * DHD * DHD, qb, kb, vb);
        k_attn<<<dim3(BB * HH, SS / 128), 256, 0, stream>>>(qb, kb, vb, ob);
        float* outp = (l == LL - 1) ? (float*)d_out : h;
        k_ffn<<<BB * SS / 32, 256, 0, stream>>>(
            ob, h, W1t + (size_t)l * FFD * EE, b1 + (size_t)l * FFD,
            W2t + (size_t)l * EE * FFD, b2 + (size_t)l * EE, outp);
    }
}

// Round 6
// 385.908 us; speedup vs baseline: 1.3604x; 1.0106x over previous
//
#include <hip/hip_runtime.h>
#include <math.h>

// Problem constants
#define BB   32
#define SS   512
#define EE   256
#define HH   8
#define LL   4
#define FFD  1024
#define DHD  32

constexpr float LN_EPS = 1e-5f;
constexpr int   NBSE   = BB * SS * EE;   // 4,194,304

typedef float  f32x4  __attribute__((ext_vector_type(4)));
typedef __bf16 bf16;
typedef __bf16 bf16x4 __attribute__((ext_vector_type(4)));
typedef __bf16 bf16x8 __attribute__((ext_vector_type(8)));

#define WAITV(n) asm volatile("s_waitcnt vmcnt(" #n ")" ::: "memory")

// async global->LDS, 16B per lane; LDS dest is wave-uniform base + lane*16B
__device__ __forceinline__ void glds16(const bf16* g, bf16* l) {
    __builtin_amdgcn_global_load_lds(
        (const __attribute__((address_space(1))) void*)g,
        (__attribute__((address_space(3))) void*)l,
        16, 0, 0);
}

// tanh-form GELU (|err| vs exact erf-GELU ~1e-3, safe within bf16 tolerance)
__device__ __forceinline__ float gelu_f(float x) {
    float u = x * x;
    float t = 1.5957691216057308f * x * (1.0f + 0.044715f * u);
    return x / (1.0f + __expf(-t));
}

// ---------------------------------------------------------------- merged weight prep
__global__ __launch_bounds__(256) void k_prep(const float* __restrict__ W1,
                                              const float* __restrict__ W2,
                                              const float* __restrict__ Wq,
                                              const float* __restrict__ Wk,
                                              const float* __restrict__ Wv,
                                              bf16* __restrict__ W1t,
                                              bf16* __restrict__ W2t,
                                              bf16* __restrict__ Wqt,
                                              bf16* __restrict__ Wkt,
                                              bf16* __restrict__ Wvt) {
    __shared__ float tile[32][33];
    int bid = blockIdx.x;
    int tx = threadIdx.x & 31, ty = threadIdx.x >> 5;   // 32 x 8
    if (bid < 2048) {
        bool isw2 = bid >= 1024;
        int id = isw2 ? bid - 1024 : bid;
        int K = isw2 ? FFD : EE, N = isw2 ? EE : FFD;
        int l = id >> 8, rem = id & 255;
        int n0, k0;
        if (isw2) { n0 = (rem & 7) * 32;  k0 = (rem >> 3) * 32; }
        else      { n0 = (rem & 31) * 32; k0 = (rem >> 5) * 32; }
        const float* in = (isw2 ? W2 : W1) + (size_t)l * K * N;
        bf16* out       = (isw2 ? W2t : W1t) + (size_t)l * K * N;
        #pragma unroll
        for (int i = 0; i < 32; i += 8)
            tile[ty + i][tx] = in[(size_t)(k0 + ty + i) * N + n0 + tx];
        __syncthreads();
        #pragma unroll
        for (int i = 0; i < 32; i += 8)
            out[(size_t)(n0 + ty + i) * K + k0 + tx] = (bf16)tile[tx][ty + i];
    } else {
        int id = bid - 2048;
        int lh = id & 31, z = id >> 5;
        const float* in = (z == 0 ? Wq : z == 1 ? Wk : Wv) + (size_t)lh * 1024;
        bf16* out       = (z == 0 ? Wqt : z == 1 ? Wkt : Wvt) + (size_t)lh * 1024;
        float scale = (z == 0) ? 0.17677669529663687f : 1.0f;
        #pragma unroll
        for (int i = 0; i < 32; i += 8)
            tile[ty + i][tx] = in[(ty + i) * 32 + tx];
        __syncthreads();
        #pragma unroll
        for (int i = 0; i < 32; i += 8)
            out[(ty + i) * 32 + tx] = (bf16)(tile[tx][ty + i] * scale);
    }
}

// ---------------------------------------------------------------- fused (addpos+)LN+QKV (MFMA)
template <bool ADDPOS>
__global__ __launch_bounds__(256) void k_lnqkv(const float* __restrict__ xin,
                                               const float* __restrict__ pos,
                                               float* __restrict__ hout,
                                               const bf16* __restrict__ Wqt,
                                               const bf16* __restrict__ Wkt,
                                               const bf16* __restrict__ Wvt,
                                               bf16* __restrict__ qb,
                                               bf16* __restrict__ kb,
                                               bf16* __restrict__ vb) {
    __shared__ __attribute__((aligned(16))) bf16 Xs[32 * 264];
    int b = blockIdx.x, s0 = blockIdx.y * 32;
    int tid = threadIdx.x, w = tid >> 6, lane = tid & 63;
    size_t rowoff = ((size_t)(b * SS + s0 + w * 8)) * EE + lane * 4;
    const float* hb = xin + rowoff;
    float4 pv;
    if (ADDPOS) pv = *(const float4*)(pos + lane * 4);
    float4 xr[8];
    #pragma unroll
    for (int i = 0; i < 8; i++)
        xr[i] = *(const float4*)(hb + (size_t)i * EE);
    if (ADDPOS) {
        #pragma unroll
        for (int i = 0; i < 8; i++) {
            xr[i].x += pv.x; xr[i].y += pv.y; xr[i].z += pv.z; xr[i].w += pv.w;
            *(float4*)(hout + rowoff + (size_t)i * EE) = xr[i];
        }
    }
    #pragma unroll
    for (int i = 0; i < 8; i++) {
        float4 v4 = xr[i];
        float sum = v4.x + v4.y + v4.z + v4.w;
        #pragma unroll
        for (int m = 1; m <= 32; m <<= 1) sum += __shfl_xor(sum, m, 64);
        float mean = sum * (1.0f / EE);
        float dx = v4.x - mean, dy = v4.y - mean, dz = v4.z - mean, dw = v4.w - mean;
        float ss = dx * dx + dy * dy + dz * dz + dw * dw;
        #pragma unroll
        for (int m = 1; m <= 32; m <<= 1) ss += __shfl_xor(ss, m, 64);
        float rstd = rsqrtf(ss * (1.0f / EE) + LN_EPS);
        bf16x4 o4 = { (bf16)(dx * rstd), (bf16)(dy * rstd), (bf16)(dz * rstd), (bf16)(dw * rstd) };
        *(bf16x4*)&Xs[(w * 8 + i) * 264 + lane * 4] = o4;
    }
    __syncthreads();
    int col = lane & 15, quad = lane >> 4;
    int rt = w & 1, hgrp = w >> 1;
    #pragma unroll
    for (int hh2 = 0; hh2 < 4; hh2++) {
        int h = hgrp * 4 + hh2;
        bf16x8 a = *(const bf16x8*)&Xs[(rt * 16 + col) * 264 + h * 32 + quad * 8];
        size_t base = ((size_t)((b * HH + h) * SS) + s0 + rt * 16) * DHD;
        #pragma unroll
        for (int nt = 0; nt < 2; nt++) {
            int e = nt * 16 + col;
            bf16x8 bq  = *(const bf16x8*)(Wqt + (h * 32 + e) * 32 + quad * 8);
            bf16x8 bk2 = *(const bf16x8*)(Wkt + (h * 32 + e) * 32 + quad * 8);
            bf16x8 bv2 = *(const bf16x8*)(Wvt + (h * 32 + e) * 32 + quad * 8);
            f32x4 z = {0.f, 0.f, 0.f, 0.f};
            f32x4 cq = __builtin_amdgcn_mfma_f32_16x16x32_bf16(bq, a, z, 0, 0, 0);
            f32x4 ck = __builtin_amdgcn_mfma_f32_16x16x32_bf16(bk2, a, z, 0, 0, 0);
            f32x4 cv = __builtin_amdgcn_mfma_f32_16x16x32_bf16(a, bv2, z, 0, 0, 0);
            bf16x4 q4 = { (bf16)cq[0], (bf16)cq[1], (bf16)cq[2], (bf16)cq[3] };
            bf16x4 k4 = { (bf16)ck[0], (bf16)ck[1], (bf16)ck[2], (bf16)ck[3] };
            size_t tb = base + (size_t)col * DHD + nt * 16 + quad * 4;
            *(bf16x4*)&qb[tb] = q4;
            *(bf16x4*)&kb[tb] = k4;
            bf16x4 vv = { (bf16)cv[0], (bf16)cv[1], (bf16)cv[2], (bf16)cv[3] };
            *(bf16x4*)&vb[(((size_t)(b * HH + h)) * DHD + e) * SS + s0 + rt * 16 + quad * 4] = vv;
        }
    }
}

// ---------------------------------------------------------------- MFMA flash attention v3
#define ATT_LDK 40
#define ATT_LDV 264
#define ATT_LDP 36
__global__ __launch_bounds__(256) void k_attn(const bf16* __restrict__ Q,
                                              const bf16* __restrict__ K,
                                              const bf16* __restrict__ VT,
                                              bf16* __restrict__ O) {
    __shared__ __attribute__((aligned(16))) bf16 Ks[256 * ATT_LDK];
    __shared__ __attribute__((aligned(16))) bf16 Vs[32 * ATT_LDV];
    __shared__ __attribute__((aligned(16))) bf16 Ps[4][16 * ATT_LDP];
    int bh = blockIdx.x;
    int q0 = blockIdx.y * 128;
    int tid = threadIdx.x;
    int w = tid >> 6, lane = tid & 63;
    int col = lane & 15, quad = lane >> 4;
    bf16x8 aq[2];
    #pragma unroll
    for (int sub = 0; sub < 2; sub++)
        aq[sub] = *(const bf16x8*)(Q + ((size_t)(bh * SS + q0 + sub * 64 + w * 16 + col)) * DHD + quad * 8);
    float lr[2] = {0.f, 0.f};
    f32x4 oacc[2][2] = {};
    int ksr = tid >> 2, ksc = (tid & 3) * 8;   // K staging: 64 rows/iter x 32 d
    int vd  = tid >> 5, vso = (tid & 31) * 8;  // VT staging: 8 d-rows/pass x 256 s
    bf16x8 kr[4], vr[4];
    #pragma unroll
    for (int it = 0; it < 4; it++) {
        kr[it] = *(const bf16x8*)(K + ((size_t)(bh * SS + it * 64 + ksr)) * DHD + ksc);
        vr[it] = *(const bf16x8*)(VT + (((size_t)bh * DHD + it * 8 + vd) * SS) + vso);
    }
    for (int ph = 0; ph < 2; ph++) {
        __syncthreads();
        #pragma unroll
        for (int it = 0; it < 4; it++) {
            *(bf16x8*)&Ks[(it * 64 + ksr) * ATT_LDK + ksc] = kr[it];
            *(bf16x8*)&Vs[(it * 8 + vd) * ATT_LDV + vso] = vr[it];
        }
        if (ph == 0) {
            #pragma unroll
            for (int it = 0; it < 4; it++) {
                kr[it] = *(const bf16x8*)(K + ((size_t)(bh * SS + 256 + it * 64 + ksr)) * DHD + ksc);
                vr[it] = *(const bf16x8*)(VT + (((size_t)bh * DHD + it * 8 + vd) * SS) + 256 + vso);
            }
        }
        __syncthreads();
        #pragma unroll
        for (int i = 0; i < 8; i++) {
            bf16x8 bk[2], bv[2];
            #pragma unroll
            for (int nt = 0; nt < 2; nt++) {
                bk[nt] = *(const bf16x8*)&Ks[(i * 32 + nt * 16 + col) * ATT_LDK + quad * 8];
                bv[nt] = *(const bf16x8*)&Vs[(nt * 16 + col) * ATT_LDV + i * 32 + quad * 8];
            }
            __builtin_amdgcn_s_setprio(1);
            #pragma unroll
            for (int sub = 0; sub < 2; sub++) {
                #pragma unroll
                for (int nt = 0; nt < 2; nt++) {
                    f32x4 z = {0.f, 0.f, 0.f, 0.f};
                    f32x4 st = __builtin_amdgcn_mfma_f32_16x16x32_bf16(bk[nt], aq[sub], z, 0, 0, 0);
                    bf16x4 p4;
                    #pragma unroll
                    for (int r = 0; r < 4; r++) {
                        float p = __expf(st[r]);
                        lr[sub] += p;
                        p4[r] = (bf16)p;
                    }
                    *(bf16x4*)&Ps[w][col * ATT_LDP + nt * 16 + quad * 4] = p4;
                }
                bf16x4 apl = *(const bf16x4*)&Ps[w][col * ATT_LDP + quad * 8];
                bf16x4 aph = *(const bf16x4*)&Ps[w][col * ATT_LDP + quad * 8 + 4];
                bf16x8 ap;
                ap[0] = apl[0]; ap[1] = apl[1]; ap[2] = apl[2]; ap[3] = apl[3];
                ap[4] = aph[0]; ap[5] = aph[1]; ap[6] = aph[2]; ap[7] = aph[3];
                #pragma unroll
                for (int nt = 0; nt < 2; nt++)
                    oacc[sub][nt] = __builtin_amdgcn_mfma_f32_16x16x32_bf16(ap, bv[nt], oacc[sub][nt], 0, 0, 0);
            }
            __builtin_amdgcn_s_setprio(0);
        }
    }
    int b = bh >> 3, hh = bh & 7;
    #pragma unroll
    for (int sub = 0; sub < 2; sub++) {
        float ls = lr[sub];
        ls += __shfl_xor(ls, 16, 64);
        ls += __shfl_xor(ls, 32, 64);
        #pragma unroll
        for (int r = 0; r < 4; r++) {
            float lrow = __shfl(ls, quad * 4 + r, 64);
            float inv = 1.0f / lrow;
            int row = q0 + sub * 64 + w * 16 + quad * 4 + r;
            size_t ob = ((size_t)(b * SS + row)) * EE + hh * 32;
            O[ob + col]      = (bf16)(oacc[sub][0][r] * inv);
            O[ob + 16 + col] = (bf16)(oacc[sub][1][r] * inv);
        }
    }
}

// ---------------------------------------------------------------- fully fused FFN v4
// r5 structure with ONE change isolated: ring depth 2 -> 3 (WAITV(8), stage g+3).
// Theory: r3/r5's depth-2 gave a staged unit only ~1 compute-unit of cover vs
// 300-600cy loaded-L2 latency -> every WAITV(4) partially stalled (MfmaUtil 13%,
// 60% idle). Depth-3 gives 2 compute-units + 2 barriers of cover. Plus T5
// setprio around the MFMA cluster (2 staggered blocks/CU = phase diversity).
// LDS: As 16K + Gs 8K + ring 3x16K + b1s 4K = 76KB -> still 2 blocks/CU.
// Math order identical to r5 -> same absmax.
__global__ __launch_bounds__(256, 2) void k_ffn(const bf16* __restrict__ ob,
                                                const float* __restrict__ hb,
                                                const bf16* __restrict__ W1t_l,
                                                const float* __restrict__ b1_l,
                                                const bf16* __restrict__ W2t_l,
                                                const float* __restrict__ b2_l,
                                                float* __restrict__ Cf) {
    __shared__ __attribute__((aligned(16))) bf16 As[32 * 256];     // 16 KB resident
    __shared__ __attribute__((aligned(16))) bf16 Gs[32 * 128];     // 8 KB
    __shared__ __attribute__((aligned(16))) bf16 Bst[3][8192];     // 3 x 16 KB ring
    __shared__ __attribute__((aligned(16))) float b1s[FFD];        // 4 KB
    int tid = threadIdx.x, w = tid >> 6, lane = tid & 63;
    int col = lane & 15, quad = lane >> 4;
    int rg = w >> 1, cg = w & 1;          // row-group (16 rows), col-group
    int row0 = blockIdx.x * 32;

    int srow = tid >> 3;                  // staging row within 32-row call chunk
    int spos = tid & 7;                   // 16B slot within 128B row
    // stage unit g (0..63): ch = g>>3, u = g&7; slot = g%3; 4 glds16/thread.
    auto stage = [&](int g) {
        int ch = g >> 3, u = g & 7, slot = g % 3;
        if (u < 4) {           // W1: 128 ff-rows x 64 k (k = u*64)
            #pragma unroll
            for (int i = 0; i < 4; i++) {
                int r = i * 32 + srow;
                glds16(W1t_l + (size_t)(ch * 128 + r) * EE + u * 64 + ((spos ^ (r & 7)) * 8),
                       &Bst[slot][i * 2048 + w * 512]);
            }
        } else {               // W2: 128 e-rows (eh half) x 64 ffk (j half)
            int j = (u - 4) >> 1, eh = (u - 4) & 1;
            #pragma unroll
            for (int i = 0; i < 4; i++) {
                int r = i * 32 + srow;
                glds16(W2t_l + (size_t)(eh * 128 + r) * FFD + ch * 128 + j * 64 + ((spos ^ (r & 7)) * 8),
                       &Bst[slot][i * 2048 + w * 512]);
            }
        }
    };
    stage(0);
    stage(1);
    stage(2);

    // b1 -> LDS
    *(float4*)&b1s[tid * 4] = *(const float4*)&b1_l[tid * 4];

    // ---- fused residual + LN prologue: wave w rows w*8 .. w*8+7
    #pragma unroll 2
    for (int rr = 0; rr < 8; rr++) {
        int r = w * 8 + rr;
        size_t g = (size_t)(row0 + r) * EE + lane * 4;
        float4 h4 = *(const float4*)(hb + g);
        bf16x4 o4 = *(const bf16x4*)(ob + g);
        float v0 = h4.x + (float)o4[0], v1 = h4.y + (float)o4[1];
        float v2 = h4.z + (float)o4[2], v3 = h4.w + (float)o4[3];
        float s1 = v0 + v1 + v2 + v3;
        float s2 = v0 * v0 + v1 * v1 + v2 * v2 + v3 * v3;
        #pragma unroll
        for (int m = 1; m <= 32; m <<= 1) {
            s1 += __shfl_xor(s1, m, 64);
            s2 += __shfl_xor(s2, m, 64);
        }
        float mean = s1 * (1.0f / EE);
        float rstd = rsqrtf(s2 * (1.0f / EE) - mean * mean + LN_EPS);
        bf16x4 a4 = { (bf16)((v0 - mean) * rstd), (bf16)((v1 - mean) * rstd),
                      (bf16)((v2 - mean) * rstd), (bf16)((v3 - mean) * rstd) };
        *(bf16x4*)&As[r * 256 + ((lane * 4) ^ ((r & 7) << 3))] = a4;
    }
    __syncthreads();   // As/b1s visible; drains vmcnt once -> units 0-2 resident

    // accO: 16 rows x 128 e per wave (e tile nta: e = nta*32 + cg*16)
    f32x4 accO[8] = {};
    int ar = rg * 16 + col;               // token row for A/G fragments
    int arx = (ar & 7) << 3;

    #pragma unroll
    for (int ch = 0; ch < 8; ch++) {
        f32x4 accG[4] = {};
        #pragma unroll
        for (int u = 0; u < 8; u++) {
            const int g = ch * 8 + u;
            const int slot = g % 3;
            if (g < 62) { WAITV(8); }
            else if (g == 62) { WAITV(4); }
            else { WAITV(0); }
            __builtin_amdgcn_s_barrier();
            if (u < 4) {
                // ---- W1 unit: accG += As(k=u*64..+63) @ W1
                bf16x8 af[2];
                #pragma unroll
                for (int kk = 0; kk < 2; kk++)
                    af[kk] = *(const bf16x8*)&As[ar * 256 + ((u * 64 + kk * 32 + quad * 8) ^ arx)];
                __builtin_amdgcn_s_setprio(1);
                #pragma unroll
                for (int nt = 0; nt < 4; nt++) {
                    int c = cg * 64 + nt * 16 + col;
                    #pragma unroll
                    for (int kk = 0; kk < 2; kk++) {
                        bf16x8 bfr = *(const bf16x8*)&Bst[slot][c * 64 + ((kk * 32 + quad * 8) ^ ((c & 7) << 3))];
                        accG[nt] = __builtin_amdgcn_mfma_f32_16x16x32_bf16(bfr, af[kk], accG[nt], 0, 0, 0);
                    }
                }
                __builtin_amdgcn_s_setprio(0);
                if (u == 3) {
                    // ---- G = gelu(accG + b1) -> Gs (swizzled)
                    #pragma unroll
                    for (int nt = 0; nt < 4; nt++) {
                        int f = cg * 64 + nt * 16 + quad * 4;
                        float4 b4 = *(const float4*)&b1s[ch * 128 + f];
                        bf16x4 g4;
                        g4[0] = (bf16)gelu_f(accG[nt][0] + b4.x);
                        g4[1] = (bf16)gelu_f(accG[nt][1] + b4.y);
                        g4[2] = (bf16)gelu_f(accG[nt][2] + b4.z);
                        g4[3] = (bf16)gelu_f(accG[nt][3] + b4.w);
                        *(bf16x4*)&Gs[ar * 128 + (f ^ arx)] = g4;
                    }
                    asm volatile("s_waitcnt lgkmcnt(0)" ::: "memory");  // publish Gs
                }
            } else {
                // ---- W2 unit: accO[eh half] += Gs(ffk=j*64..+63) @ W2
                const int j = (u - 4) >> 1, eh = (u - 4) & 1;
                bf16x8 af2[2];
                #pragma unroll
                for (int kk = 0; kk < 2; kk++)
                    af2[kk] = *(const bf16x8*)&Gs[ar * 128 + ((j * 64 + kk * 32 + quad * 8) ^ arx)];
                __builtin_amdgcn_s_setprio(1);
                #pragma unroll
                for (int nt = 0; nt < 4; nt++) {
                    int c = nt * 32 + cg * 16 + col;   // e row within slot half
                    #pragma unroll
                    for (int kk = 0; kk < 2; kk++) {
                        bf16x8 bfr = *(const bf16x8*)&Bst[slot][c * 64 + ((kk * 32 + quad * 8) ^ ((c & 7) << 3))];
                        accO[eh * 4 + nt] = __builtin_amdgcn_mfma_f32_16x16x32_bf16(bfr, af2[kk], accO[eh * 4 + nt], 0, 0, 0);
                    }
                }
                __builtin_amdgcn_s_setprio(0);
            }
            __builtin_amdgcn_s_barrier();   // slot reads done -> restage safe
            if (g + 3 < 64) stage(g + 3);   // depth-3 prefetch into slot (g+3)%3
        }
    }

    // ---- epilogue: + b2 + residual (h + ob), f32 out
    #pragma unroll
    for (int nta = 0; nta < 8; nta++) {
        int eh = nta >> 2;
        int row = row0 + rg * 16 + col;
        int cc = eh * 128 + (nta & 3) * 32 + cg * 16 + quad * 4;
        float4 b4 = *(const float4*)&b2_l[cc];
        float4 h4 = *(const float4*)&hb[(size_t)row * EE + cc];
        bf16x4 o4 = *(const bf16x4*)&ob[(size_t)row * EE + cc];
        float4 out;
        out.x = accO[nta][0] + b4.x + h4.x + (float)o4[0];
        out.y = accO[nta][1] + b4.y + h4.y + (float)o4[1];
        out.z = accO[nta][2] + b4.z + h4.z + (float)o4[2];
        out.w = accO[nta][3] + b4.w + h4.w + (float)o4[3];
        *(float4*)&Cf[(size_t)row * EE + cc] = out;
    }
}

// ---------------------------------------------------------------- launch
extern "C" void kernel_launch(void* const* d_in, const int* in_sizes, int n_in,
                              void* d_out, int out_size, void* d_ws, size_t ws_size,
                              hipStream_t stream) {
    (void)in_sizes; (void)n_in; (void)out_size; (void)ws_size;
    const float* x   = (const float*)d_in[0];
    const float* pos = (const float*)d_in[1];
    const float* Wq  = (const float*)d_in[2];
    const float* Wk  = (const float*)d_in[3];
    const float* Wv  = (const float*)d_in[4];
    const float* W1  = (const float*)d_in[5];
    const float* b1  = (const float*)d_in[6];
    const float* W2  = (const float*)d_in[7];
    const float* b2  = (const float*)d_in[8];

    float* ws = (float*)d_ws;
    size_t N = (size_t)NBSE;
    float* h  = ws;                          // [0 .. 16MB) f32 residual stream
    bf16* ob  = (bf16*)(ws + N);             // [16 .. 24MB) attention out, concat layout
    bf16* qb  = (bf16*)(ws + 2 * N);         // [32 .. 40MB)
    bf16* kb  = qb + N;                      // [40 .. 48MB)
    bf16* vb  = kb + N;                      // [48 .. 56MB) (VT layout [bh][d][s])
    bf16* W1t = (bf16*)(ws + 4 * N);         // [64MB ..)
    bf16* W2t = W1t + (size_t)LL * EE * FFD;
    bf16* Wqt = W2t + (size_t)LL * EE * FFD;
    bf16* Wkt = Wqt + (size_t)LL * HH * DHD * DHD;
    bf16* Wvt = Wkt + (size_t)LL * HH * DHD * DHD;

    k_prep<<<2144, 256, 0, stream>>>(W1, W2, Wq, Wk, Wv, W1t, W2t, Wqt, Wkt, Wvt);
    for (int l = 0; l < LL; l++) {
        if (l == 0)
            k_lnqkv<true><<<dim3(BB, SS / 32), 256, 0, stream>>>(
                x, pos, h, Wqt, Wkt, Wvt, qb, kb, vb);
        else
            k_lnqkv<false><<<dim3(BB, SS / 32), 256, 0, stream>>>(
                h, nullptr, nullptr,
                Wqt + (size_t)l * HH * DHD * DHD, Wkt + (size_t)l * HH * DHD * DHD,
                Wvt + (size_t)l * HH * DHD * DHD, qb, kb, vb);
        k_attn<<<dim3(BB * HH, SS / 128), 256, 0, stream>>>(qb, kb, vb, ob);
        float* outp = (l == LL - 1) ? (float*)d_out : h;
        k_ffn<<<BB * SS / 32, 256, 0, stream>>>(
            ob, h, W1t + (size_t)l * FFD * EE, b1 + (size_t)l * FFD,
            W2t + (size_t)l * EE * FFD, b2 + (size_t)l * EE, outp);
    }
}